// Round 7
// baseline (160.069 us; speedup 1.0000x reference)
//
#include <hip/hip_runtime.h>
#include <hip/hip_bf16.h>
#include <stdint.h>

#define BATCH 4
#define SEQ   4096
#define EMB   1024
#define HD    64

typedef __bf16 bf16x8 __attribute__((ext_vector_type(8)));
typedef float  f32x4  __attribute__((ext_vector_type(4)));
typedef unsigned short u16;

union ABFrag { u16 s[8]; bf16x8 v; };

__device__ __forceinline__ u16 f2bf_rne(float f) {
    union { float f; uint32_t u; } cv; cv.f = f;
    uint32_t u = cv.u;
    return (u16)((u + 0x7fffu + ((u >> 16) & 1u)) >> 16);
}
__device__ __forceinline__ float bf2f(u16 h) {
    union { uint32_t u; float f; } cv; cv.u = ((uint32_t)h) << 16;
    return cv.f;
}
__device__ __forceinline__ void gld16(const void* g, void* l) {
    __builtin_amdgcn_global_load_lds(
        (const __attribute__((address_space(1))) void*)g,
        (__attribute__((address_space(3))) void*)l, 16, 0, 0);
}

// ---------------------------------------------------------------------------
// Kernel 0: W (1024,64) fp32 x3 -> Wt bf16 [3][64][1024]  (transposed)
// ---------------------------------------------------------------------------
__global__ __launch_bounds__(256) void wt_kernel(
        const float* __restrict__ Wq, const float* __restrict__ Wk,
        const float* __restrict__ Wv, u16* __restrict__ Wt) {
    int idx = blockIdx.x * 256 + threadIdx.x;
    int i = idx >> 16;
    int r = idx & 65535;
    int n = r >> 10;
    int k = r & 1023;
    const float* W = (i == 0) ? Wq : (i == 1) ? Wk : Wv;
    Wt[idx] = f2bf_rne(W[k * HD + n]);
}

// ---------------------------------------------------------------------------
// Kernel 1: QKV projection v3 — barrier-free K-loop.
// Grid 192 = 3 weights x 64 rowblocks (256 rows). 512 threads = 8 waves.
// The ENTIRE W-slab for this block's weight (64 cols x 1024 k bf16 = 128 KB)
// is staged into LDS once, then ZERO barriers in the K-loop.
// NOTE global_load_lds contract: PER-LANE global address, wave-uniform LDS
// base; lane i lands at base + i*16 B. (R6 bug: missing lane term.)
// ---------------------------------------------------------------------------
__global__ __launch_bounds__(512) void qkv_kernel(
        const float* __restrict__ x, const u16* __restrict__ Wt,
        u16* __restrict__ Qw, u16* __restrict__ Kw, u16* __restrict__ Vt) {
    __shared__ u16 wl[64 * 1032];   // 129 KB: 64 rows x (1024 + 8 pad) u16

    const int t    = threadIdx.x;
    const int wave = t >> 6;        // 0..7
    const int lane = t & 63;
    const int m16  = lane & 15;
    const int quad = lane >> 4;
    const int wv   = blockIdx.x >> 6;     // weight 0..2
    const int rb   = blockIdx.x & 63;     // rowblock 0..63

    // ---- stage whole W-slab: 128 x 1KB DMA, 16 per wave ----
    {
        const u16* wsrc = Wt + (wv << 16);
#pragma unroll
        for (int j = 0; j < 16; ++j) {
            const int idx = (wave << 4) + j;
            const int n   = idx >> 1;
            const int hh  = idx & 1;
            gld16(wsrc + (n << 10) + (hh << 9) + (lane << 3),   // per-lane gaddr!
                  &wl[n * 1032 + (hh << 9)]);
        }
    }
    __syncthreads();   // the ONLY barrier (drains DMA via vmcnt(0))

    // ---- 2 row-tiles per wave, processed jointly ----
    const int rtA  = (rb << 4) + (wave << 1);
    const int rowA = (rtA << 4) + m16;
    const float* xpA = x + (size_t)rowA * EMB + (quad << 3);
    const float* xpB = xpA + (16 * EMB);

    f32x4 accA[4], accB[4];
#pragma unroll
    for (int tt = 0; tt < 4; ++tt) {
        accA[tt] = (f32x4){0.f, 0.f, 0.f, 0.f};
        accB[tt] = (f32x4){0.f, 0.f, 0.f, 0.f};
    }

    const u16* wbase = &wl[m16 * 1032 + (quad << 3)];

#pragma unroll 2
    for (int kt = 0; kt < 32; ++kt) {
        const float4 a0A = *(const float4*)(xpA + (kt << 5));
        const float4 a1A = *(const float4*)(xpA + (kt << 5) + 4);
        const float4 a0B = *(const float4*)(xpB + (kt << 5));
        const float4 a1B = *(const float4*)(xpB + (kt << 5) + 4);
        ABFrag afA, afB;
        afA.s[0] = f2bf_rne(a0A.x); afA.s[1] = f2bf_rne(a0A.y);
        afA.s[2] = f2bf_rne(a0A.z); afA.s[3] = f2bf_rne(a0A.w);
        afA.s[4] = f2bf_rne(a1A.x); afA.s[5] = f2bf_rne(a1A.y);
        afA.s[6] = f2bf_rne(a1A.z); afA.s[7] = f2bf_rne(a1A.w);
        afB.s[0] = f2bf_rne(a0B.x); afB.s[1] = f2bf_rne(a0B.y);
        afB.s[2] = f2bf_rne(a0B.z); afB.s[3] = f2bf_rne(a0B.w);
        afB.s[4] = f2bf_rne(a1B.x); afB.s[5] = f2bf_rne(a1B.y);
        afB.s[6] = f2bf_rne(a1B.z); afB.s[7] = f2bf_rne(a1B.w);
#pragma unroll
        for (int tt = 0; tt < 4; ++tt) {
            const bf16x8 bf = *(const bf16x8*)(wbase + tt * (16 * 1032) + (kt << 5));
            accA[tt] = __builtin_amdgcn_mfma_f32_16x16x32_bf16(afA.v, bf, accA[tt], 0, 0, 0);
            accB[tt] = __builtin_amdgcn_mfma_f32_16x16x32_bf16(afB.v, bf, accB[tt], 0, 0, 0);
        }
    }

    // ---- epilogue: C layout rows quad*4+reg, col tt*16+m16 ----
#pragma unroll
    for (int half = 0; half < 2; ++half) {
        const f32x4* acc = half ? accB : accA;
        const int rowbase = ((rtA + half) << 4) + (quad << 2);
        const int bidx = rowbase >> 12;
        const int t0   = rowbase & 4095;
#pragma unroll
        for (int tt = 0; tt < 4; ++tt) {
            const int col = (tt << 4) + m16;
            if (wv == 0) {
#pragma unroll
                for (int reg = 0; reg < 4; ++reg)
                    Qw[(size_t)(rowbase + reg) * HD + col] = f2bf_rne(acc[tt][reg] * 0.03125f);
            } else if (wv == 1) {
#pragma unroll
                for (int reg = 0; reg < 4; ++reg)
                    Kw[(size_t)(rowbase + reg) * HD + col] = f2bf_rne(acc[tt][reg]);
            } else {
                ushort4 vv;
                vv.x = f2bf_rne(acc[tt][0]); vv.y = f2bf_rne(acc[tt][1]);
                vv.z = f2bf_rne(acc[tt][2]); vv.w = f2bf_rne(acc[tt][3]);
                *(ushort4*)(Vt + (size_t)((bidx << 6) + col) * SEQ + t0) = vv;
            }
        }
    }
}

// ---------------------------------------------------------------------------
// Kernel 2: split-K causal flash attention, S^T formulation, LDS-staged K/V.
// Per jt: K tile (64 kpos x 64 d) and V tile (64 d x 64 kpos) DMA'd into
// double-buffered LDS (XOR-chunk swizzle), shared by all 4 waves.
// Grid 1024 balanced: qt = h ^ {0,63,32,31}[r], chunk jt = r, r+4, ... <= qt.
// ---------------------------------------------------------------------------
__global__ __launch_bounds__(256) void attn_part_kernel(
        const u16* __restrict__ Qw, const u16* __restrict__ Kw,
        const u16* __restrict__ Vt, u16* __restrict__ Opart,
        float* __restrict__ Mp, float* __restrict__ Lp) {
    __shared__ u16 kv[2][2][4096];     // [buf][K/V][64 rows x 8 chunks] = 32 KB
    __shared__ u16 ldsP[4][16 * 72];   // per-wave P[q][k], row stride 72 u16

    const int pid = blockIdx.x;
    const int r   = pid >> 8;
    const int i   = pid & 255;
    const int b   = i & 3;
    const int h   = i >> 2;
    const int qt  = h ^ (int)((0x1f203f00u >> (r * 8)) & 63u);  // {0,63,32,31}[r]
    const int c   = r;
    const int p_out = (((b << 6) + qt) << 2) + c;

    const int wave = threadIdx.x >> 6;
    const int lane = threadIdx.x & 63;
    const int m16  = lane & 15;
    const int quad = lane >> 4;

    #define ISSUE_KV(buf_, jt_) do {                                           \
        const int r8_ = lane >> 3, c8_ = lane & 7;                             \
        const int kc_ = c8_ ^ r8_;                                             \
        _Pragma("unroll")                                                      \
        for (int j_ = 0; j_ < 2; ++j_) {                                       \
            const int row_ = ((wave * 2 + j_) << 3) + r8_;   /* 0..63 */       \
            gld16(Kw + ((size_t)(b * SEQ + ((jt_) << 6) + row_) << 6) + (kc_ << 3), \
                  &kv[buf_][0][(wave * 2 + j_) << 9]);                         \
            gld16(Vt + (size_t)((b << 6) + row_) * SEQ + ((jt_) << 6) + (kc_ << 3), \
                  &kv[buf_][1][(wave * 2 + j_) << 9]);                         \
        }                                                                      \
    } while (0)

    // Q fragment as B-operand: n = m16 = q-row, k = quad*8+j
    const int qrow = (qt << 6) + (wave << 4) + m16;
    const u16* qbase = Qw + ((size_t)(b * SEQ + qrow) << 6);
    const bf16x8 qf0 = *(const bf16x8*)(qbase + (quad << 3));
    const bf16x8 qf1 = *(const bf16x8*)(qbase + 32 + (quad << 3));

    f32x4 acc[4];     // O^T: lane q = m16, d = dt*16 + quad*4 + reg
#pragma unroll
    for (int dt = 0; dt < 4; ++dt) acc[dt] = (f32x4){0.f, 0.f, 0.f, 0.f};
    float m_i = -3.0e38f;
    float l_i = 0.f;

    u16* ldsW = &ldsP[wave][0];
    const int xs0 = (quad ^ (m16 & 7)) << 3;         // chunk slots for k-win 0
    const int xs1 = (((quad + 4)) ^ (m16 & 7)) << 3; // and k-win 1 (in u16)

    if (c <= qt) ISSUE_KV(0, c);

    int buf = 0;
    for (int jt = c; jt <= qt; jt += 4) {
        __syncthreads();                 // DMA of buf landed; buf^1 free
        if (jt + 4 <= qt) ISSUE_KV(buf ^ 1, jt + 4);

        // ---- S^T = K @ Q^T : A = K-frag from LDS ----
        f32x4 s[4];
#pragma unroll
        for (int mt = 0; mt < 4; ++mt) {
            const int base = ((mt << 4) + m16) << 6;
            bf16x8 k0 = *(const bf16x8*)&kv[buf][0][base + xs0];
            bf16x8 k1 = *(const bf16x8*)&kv[buf][0][base + xs1];
            s[mt] = (f32x4){0.f, 0.f, 0.f, 0.f};
            s[mt] = __builtin_amdgcn_mfma_f32_16x16x32_bf16(k0, qf0, s[mt], 0, 0, 0);
            s[mt] = __builtin_amdgcn_mfma_f32_16x16x32_bf16(k1, qf1, s[mt], 0, 0, 0);
        }

        if (jt == qt) {   // diagonal tile: mask k_in > q_in
            const int q_in = (wave << 4) + m16;
#pragma unroll
            for (int mt = 0; mt < 4; ++mt) {
                const int k_in = (mt << 4) + (quad << 2);
#pragma unroll
                for (int reg = 0; reg < 4; ++reg)
                    if (k_in + reg > q_in) s[mt][reg] = -3.0e38f;
            }
        }

        // ---- online softmax: lane owns one q-row; 2 cross-quad hops ----
        float tm = fmaxf(fmaxf(s[0][0], s[0][1]), fmaxf(s[0][2], s[0][3]));
#pragma unroll
        for (int mt = 1; mt < 4; ++mt)
            tm = fmaxf(tm, fmaxf(fmaxf(s[mt][0], s[mt][1]), fmaxf(s[mt][2], s[mt][3])));
        tm = fmaxf(tm, __shfl_xor(tm, 16));
        tm = fmaxf(tm, __shfl_xor(tm, 32));

        const float mnew  = fmaxf(m_i, tm);
        const float alpha = __expf(m_i - mnew);
        m_i = mnew;

        float psum = 0.f;
#pragma unroll
        for (int mt = 0; mt < 4; ++mt) {
            const float p0 = __expf(s[mt][0] - mnew);
            const float p1 = __expf(s[mt][1] - mnew);
            const float p2 = __expf(s[mt][2] - mnew);
            const float p3 = __expf(s[mt][3] - mnew);
            psum += (p0 + p1) + (p2 + p3);
            ushort4 pv;
            pv.x = f2bf_rne(p0); pv.y = f2bf_rne(p1);
            pv.z = f2bf_rne(p2); pv.w = f2bf_rne(p3);
            *(ushort4*)(ldsW + m16 * 72 + (mt << 4) + (quad << 2)) = pv;
        }
        l_i = l_i * alpha + psum;
#pragma unroll
        for (int dt = 0; dt < 4; ++dt)
#pragma unroll
            for (int reg = 0; reg < 4; ++reg) acc[dt][reg] *= alpha;

        // ---- O^T += V^T @ P^T : A = V-frag from LDS ----
        const bf16x8 p0 = *(const bf16x8*)(ldsW + m16 * 72 + (quad << 3));
        const bf16x8 p1 = *(const bf16x8*)(ldsW + m16 * 72 + 32 + (quad << 3));
#pragma unroll
        for (int dt = 0; dt < 4; ++dt) {
            const int base = ((dt << 4) + m16) << 6;
            bf16x8 v0 = *(const bf16x8*)&kv[buf][1][base + xs0];
            bf16x8 v1 = *(const bf16x8*)&kv[buf][1][base + xs1];
            acc[dt] = __builtin_amdgcn_mfma_f32_16x16x32_bf16(v0, p0, acc[dt], 0, 0, 0);
            acc[dt] = __builtin_amdgcn_mfma_f32_16x16x32_bf16(v1, p1, acc[dt], 0, 0, 0);
        }
        buf ^= 1;
    }
    #undef ISSUE_KV

    float l = l_i;
    l += __shfl_xor(l, 16);
    l += __shfl_xor(l, 32);

    u16* ob = Opart + (size_t)p_out * 4096;
    const int qin = (wave << 4) + m16;
#pragma unroll
    for (int dt = 0; dt < 4; ++dt) {
        ushort4 vv;
        vv.x = f2bf_rne(acc[dt][0]); vv.y = f2bf_rne(acc[dt][1]);
        vv.z = f2bf_rne(acc[dt][2]); vv.w = f2bf_rne(acc[dt][3]);
        *(ushort4*)(ob + qin * 64 + (dt << 4) + (quad << 2)) = vv;
    }
    if (quad == 0) {
        Mp[p_out * 64 + qin] = m_i;
        Lp[p_out * 64 + qin] = l;
    }
}

// ---------------------------------------------------------------------------
// Kernel 3: combine the 4 chunk partials per (b, qtile, rowquarter), normalize.
// Grid 1024, vectorized ushort4 reads / float4 writes.
// ---------------------------------------------------------------------------
__global__ __launch_bounds__(256) void combine_kernel(
        const u16* __restrict__ Opart, const float* __restrict__ Mp,
        const float* __restrict__ Lp, float* __restrict__ out) {
    __shared__ float sm[4][16];
    __shared__ float sl[4][16];
    const int bq = blockIdx.x >> 2;          // b*64 + qt
    const int rq = blockIdx.x & 3;           // row quarter
    const int pidbase = bq << 2;
    const int t = threadIdx.x;
    if (t < 64) {
        const int cc = t >> 4, rr = t & 15;
        sm[cc][rr] = Mp[(pidbase + cc) * 64 + rq * 16 + rr];
        sl[cc][rr] = Lp[(pidbase + cc) * 64 + rq * 16 + rr];
    }
    __syncthreads();

    const int row_l = t >> 4;                // 0..15
    const int c4    = (t & 15) << 2;         // col base
    const int row   = rq * 16 + row_l;

    const float M = fmaxf(fmaxf(sm[0][row_l], sm[1][row_l]),
                          fmaxf(sm[2][row_l], sm[3][row_l]));
    float n0 = 0.f, n1 = 0.f, n2 = 0.f, n3 = 0.f, den = 0.f;
#pragma unroll
    for (int cc = 0; cc < 4; ++cc) {
        const float w = __expf(sm[cc][row_l] - M);
        den += w * sl[cc][row_l];
        const ushort4 op = *(const ushort4*)&Opart[
                (size_t)(pidbase + cc) * 4096 + row * 64 + c4];
        n0 += w * bf2f(op.x); n1 += w * bf2f(op.y);
        n2 += w * bf2f(op.z); n3 += w * bf2f(op.w);
    }
    const float rd = 1.0f / den;
    float4 o; o.x = n0 * rd; o.y = n1 * rd; o.z = n2 * rd; o.w = n3 * rd;
    *(float4*)&out[((size_t)bq << 12) + (row << 6) + c4] = o;
}

// ---------------------------------------------------------------------------
extern "C" void kernel_launch(void* const* d_in, const int* in_sizes, int n_in,
                              void* d_out, int out_size, void* d_ws, size_t ws_size,
                              hipStream_t stream) {
    const float* x  = (const float*)d_in[0];
    const float* Wq = (const float*)d_in[1];
    const float* Wk = (const float*)d_in[2];
    const float* Wv = (const float*)d_in[3];
    float* out = (float*)d_out;

    char* ws = (char*)d_ws;
    u16* Qw    = (u16*)(ws);                        // 2 MB
    u16* Kw    = (u16*)(ws + (2u << 20));           // 2 MB
    u16* Vt    = (u16*)(ws + (4u << 20));           // 2 MB  [b][64][T]
    u16* Wt    = (u16*)(ws + (6u << 20));           // 384 KB
    u16* Opart = (u16*)(ws + (13u << 19));          // 8 MB
    float* Mp  = (float*)(ws + (29u << 19));        // 256 KB
    float* Lp  = (float*)(ws + (59u << 18));        // 256 KB

    wt_kernel<<<768, 256, 0, stream>>>(Wq, Wk, Wv, Wt);
    qkv_kernel<<<192, 512, 0, stream>>>(x, Wt, Qw, Kw, Vt);
    attn_part_kernel<<<1024, 256, 0, stream>>>(Qw, Kw, Vt, Opart, Mp, Lp);
    combine_kernel<<<1024, 256, 0, stream>>>(Opart, Mp, Lp, out);
}

// Round 8
// 153.863 us; speedup vs baseline: 1.0403x; 1.0403x over previous
//
#include <hip/hip_runtime.h>
#include <hip/hip_bf16.h>
#include <stdint.h>

#define BATCH 4
#define SEQ   4096
#define EMB   1024
#define HD    64

typedef __bf16 bf16x8 __attribute__((ext_vector_type(8)));
typedef float  f32x4  __attribute__((ext_vector_type(4)));
typedef unsigned short u16;

union ABFrag { u16 s[8]; bf16x8 v; };

__device__ __forceinline__ u16 f2bf_rne(float f) {
    union { float f; uint32_t u; } cv; cv.f = f;
    uint32_t u = cv.u;
    return (u16)((u + 0x7fffu + ((u >> 16) & 1u)) >> 16);
}
__device__ __forceinline__ float bf2f(u16 h) {
    union { uint32_t u; float f; } cv; cv.u = ((uint32_t)h) << 16;
    return cv.f;
}
__device__ __forceinline__ void gld16(const void* g, void* l) {
    __builtin_amdgcn_global_load_lds(
        (const __attribute__((address_space(1))) void*)g,
        (__attribute__((address_space(3))) void*)l, 16, 0, 0);
}

// ---------------------------------------------------------------------------
// Kernel 0: W (1024,64) fp32 x3 -> Wt bf16 [3][64][1024]  (transposed)
// ---------------------------------------------------------------------------
__global__ __launch_bounds__(256) void wt_kernel(
        const float* __restrict__ Wq, const float* __restrict__ Wk,
        const float* __restrict__ Wv, u16* __restrict__ Wt) {
    int idx = blockIdx.x * 256 + threadIdx.x;
    int i = idx >> 16;
    int r = idx & 65535;
    int n = r >> 10;
    int k = r & 1023;
    const float* W = (i == 0) ? Wq : (i == 1) ? Wk : Wv;
    Wt[idx] = f2bf_rne(W[k * HD + n]);
}

// ---------------------------------------------------------------------------
// Kernel 1: QKV projection v3 — barrier-free K-loop. UNCHANGED from R7:
// three different structures (R4 dbuf / R5 direct-x / R7 slab) all measure
// ~42 us == the ws-poison writeback window; qkv is ambient-HBM bound.
// ---------------------------------------------------------------------------
__global__ __launch_bounds__(512) void qkv_kernel(
        const float* __restrict__ x, const u16* __restrict__ Wt,
        u16* __restrict__ Qw, u16* __restrict__ Kw, u16* __restrict__ Vt) {
    __shared__ u16 wl[64 * 1032];   // 129 KB: 64 rows x (1024 + 8 pad) u16

    const int t    = threadIdx.x;
    const int wave = t >> 6;        // 0..7
    const int lane = t & 63;
    const int m16  = lane & 15;
    const int quad = lane >> 4;
    const int wv   = blockIdx.x >> 6;     // weight 0..2
    const int rb   = blockIdx.x & 63;     // rowblock 0..63

    {
        const u16* wsrc = Wt + (wv << 16);
#pragma unroll
        for (int j = 0; j < 16; ++j) {
            const int idx = (wave << 4) + j;
            const int n   = idx >> 1;
            const int hh  = idx & 1;
            gld16(wsrc + (n << 10) + (hh << 9) + (lane << 3),
                  &wl[n * 1032 + (hh << 9)]);
        }
    }
    __syncthreads();   // the ONLY barrier

    const int rtA  = (rb << 4) + (wave << 1);
    const int rowA = (rtA << 4) + m16;
    const float* xpA = x + (size_t)rowA * EMB + (quad << 3);
    const float* xpB = xpA + (16 * EMB);

    f32x4 accA[4], accB[4];
#pragma unroll
    for (int tt = 0; tt < 4; ++tt) {
        accA[tt] = (f32x4){0.f, 0.f, 0.f, 0.f};
        accB[tt] = (f32x4){0.f, 0.f, 0.f, 0.f};
    }

    const u16* wbase = &wl[m16 * 1032 + (quad << 3)];

#pragma unroll 2
    for (int kt = 0; kt < 32; ++kt) {
        const float4 a0A = *(const float4*)(xpA + (kt << 5));
        const float4 a1A = *(const float4*)(xpA + (kt << 5) + 4);
        const float4 a0B = *(const float4*)(xpB + (kt << 5));
        const float4 a1B = *(const float4*)(xpB + (kt << 5) + 4);
        ABFrag afA, afB;
        afA.s[0] = f2bf_rne(a0A.x); afA.s[1] = f2bf_rne(a0A.y);
        afA.s[2] = f2bf_rne(a0A.z); afA.s[3] = f2bf_rne(a0A.w);
        afA.s[4] = f2bf_rne(a1A.x); afA.s[5] = f2bf_rne(a1A.y);
        afA.s[6] = f2bf_rne(a1A.z); afA.s[7] = f2bf_rne(a1A.w);
        afB.s[0] = f2bf_rne(a0B.x); afB.s[1] = f2bf_rne(a0B.y);
        afB.s[2] = f2bf_rne(a0B.z); afB.s[3] = f2bf_rne(a0B.w);
        afB.s[4] = f2bf_rne(a1B.x); afB.s[5] = f2bf_rne(a1B.y);
        afB.s[6] = f2bf_rne(a1B.z); afB.s[7] = f2bf_rne(a1B.w);
#pragma unroll
        for (int tt = 0; tt < 4; ++tt) {
            const bf16x8 bf = *(const bf16x8*)(wbase + tt * (16 * 1032) + (kt << 5));
            accA[tt] = __builtin_amdgcn_mfma_f32_16x16x32_bf16(afA.v, bf, accA[tt], 0, 0, 0);
            accB[tt] = __builtin_amdgcn_mfma_f32_16x16x32_bf16(afB.v, bf, accB[tt], 0, 0, 0);
        }
    }

#pragma unroll
    for (int half = 0; half < 2; ++half) {
        const f32x4* acc = half ? accB : accA;
        const int rowbase = ((rtA + half) << 4) + (quad << 2);
        const int bidx = rowbase >> 12;
        const int t0   = rowbase & 4095;
#pragma unroll
        for (int tt = 0; tt < 4; ++tt) {
            const int col = (tt << 4) + m16;
            if (wv == 0) {
#pragma unroll
                for (int reg = 0; reg < 4; ++reg)
                    Qw[(size_t)(rowbase + reg) * HD + col] = f2bf_rne(acc[tt][reg] * 0.03125f);
            } else if (wv == 1) {
#pragma unroll
                for (int reg = 0; reg < 4; ++reg)
                    Kw[(size_t)(rowbase + reg) * HD + col] = f2bf_rne(acc[tt][reg]);
            } else {
                ushort4 vv;
                vv.x = f2bf_rne(acc[tt][0]); vv.y = f2bf_rne(acc[tt][1]);
                vv.z = f2bf_rne(acc[tt][2]); vv.w = f2bf_rne(acc[tt][3]);
                *(ushort4*)(Vt + (size_t)((bidx << 6) + col) * SEQ + t0) = vv;
            }
        }
    }
}

// ---------------------------------------------------------------------------
// Kernel 2: split-K causal flash attention v3 — 128 q-rows/block, 8 waves.
// Each 16 KB KV DMA now feeds 8 waves (2x MFMA per barrier vs R7) and total
// barrier count halves. Grid 512 = (r,s): b = s>>6, i0 = (s>>1)&31, ch = s&1;
// r flips to (31-i0, partner c) so each CU's 2 blocks sum to ~16.5 iters.
// Waves 0-3 skip the final odd KV tile (compute guarded; barriers uniform).
// ---------------------------------------------------------------------------
__global__ __launch_bounds__(512) void attn_part_kernel(
        const u16* __restrict__ Qw, const u16* __restrict__ Kw,
        const u16* __restrict__ Vt, u16* __restrict__ Opart,
        float* __restrict__ Mp, float* __restrict__ Lp) {
    __shared__ u16 kv[2][2][4096];     // [buf][K/V][64 rows x 8 chunks] = 32 KB
    __shared__ u16 ldsP[8][16 * 72];   // per-wave P[q][k], row stride 72 u16

    const int pid = blockIdx.x;        // 0..511
    const int r   = pid >> 8;
    const int s   = pid & 255;
    const int b   = s >> 6;
    const int i0  = (s >> 1) & 31;
    const int ch  = s & 1;
    const int i   = r ? (31 - i0) : i0;       // q-tile (128 rows) 0..31
    const int c   = (ch << 1) | r;            // chunk 0..3
    const int jmax = (i << 1) + 1;            // block's last KV tile
    const int p_out = (((b << 5) + i) << 2) + c;

    const int wave = threadIdx.x >> 6;        // 0..7
    const int lane = threadIdx.x & 63;
    const int m16  = lane & 15;
    const int quad = lane >> 4;
    const int jend = (i << 1) + (wave >> 2);  // wave's last useful KV tile

    #define ISSUE_KV(buf_, jt_) do {                                           \
        const int r8_ = lane >> 3, c8_ = lane & 7;                             \
        const int kc_ = c8_ ^ r8_;                                             \
        const int row_ = (wave << 3) + r8_;             /* 0..63 */            \
        gld16(Kw + ((size_t)(b * SEQ + ((jt_) << 6) + row_) << 6) + (kc_ << 3),\
              &kv[buf_][0][wave << 9]);                                        \
        gld16(Vt + (size_t)((b << 6) + row_) * SEQ + ((jt_) << 6) + (kc_ << 3),\
              &kv[buf_][1][wave << 9]);                                        \
    } while (0)

    // Q fragment as B-operand: n = m16 = q-row, k = quad*8+j
    const int qrow = (i << 7) + (wave << 4) + m16;
    const u16* qbase = Qw + ((size_t)(b * SEQ + qrow) << 6);
    const bf16x8 qf0 = *(const bf16x8*)(qbase + (quad << 3));
    const bf16x8 qf1 = *(const bf16x8*)(qbase + 32 + (quad << 3));

    f32x4 acc[4];     // O^T: lane q = m16, d = dt*16 + quad*4 + reg
#pragma unroll
    for (int dt = 0; dt < 4; ++dt) acc[dt] = (f32x4){0.f, 0.f, 0.f, 0.f};
    float m_i = -3.0e38f;
    float l_i = 0.f;

    u16* ldsW = &ldsP[wave][0];
    const int xs0 = (quad ^ (m16 & 7)) << 3;
    const int xs1 = ((quad + 4) ^ (m16 & 7)) << 3;

    if (c <= jmax) ISSUE_KV(0, c);

    int buf = 0;
    for (int jt = c; jt <= jmax; jt += 4) {
        __syncthreads();                 // DMA of buf landed; buf^1 free
        if (jt + 4 <= jmax) ISSUE_KV(buf ^ 1, jt + 4);

        if (jt <= jend) {
            // ---- S^T = K @ Q^T : A = K-frag from LDS ----
            f32x4 sv[4];
#pragma unroll
            for (int mt = 0; mt < 4; ++mt) {
                const int base = ((mt << 4) + m16) << 6;
                bf16x8 k0 = *(const bf16x8*)&kv[buf][0][base + xs0];
                bf16x8 k1 = *(const bf16x8*)&kv[buf][0][base + xs1];
                sv[mt] = (f32x4){0.f, 0.f, 0.f, 0.f};
                sv[mt] = __builtin_amdgcn_mfma_f32_16x16x32_bf16(k0, qf0, sv[mt], 0, 0, 0);
                sv[mt] = __builtin_amdgcn_mfma_f32_16x16x32_bf16(k1, qf1, sv[mt], 0, 0, 0);
            }

            if (jt == jend) {   // diagonal tile for this wave
                const int q_in = ((wave & 3) << 4) + m16;
#pragma unroll
                for (int mt = 0; mt < 4; ++mt) {
                    const int k_in = (mt << 4) + (quad << 2);
#pragma unroll
                    for (int reg = 0; reg < 4; ++reg)
                        if (k_in + reg > q_in) sv[mt][reg] = -3.0e38f;
                }
            }

            // ---- online softmax: lane owns one q-row; 2 cross-quad hops ----
            float tm = fmaxf(fmaxf(sv[0][0], sv[0][1]), fmaxf(sv[0][2], sv[0][3]));
#pragma unroll
            for (int mt = 1; mt < 4; ++mt)
                tm = fmaxf(tm, fmaxf(fmaxf(sv[mt][0], sv[mt][1]), fmaxf(sv[mt][2], sv[mt][3])));
            tm = fmaxf(tm, __shfl_xor(tm, 16));
            tm = fmaxf(tm, __shfl_xor(tm, 32));

            const float mnew  = fmaxf(m_i, tm);
            const float alpha = __expf(m_i - mnew);
            m_i = mnew;

            float psum = 0.f;
#pragma unroll
            for (int mt = 0; mt < 4; ++mt) {
                const float p0 = __expf(sv[mt][0] - mnew);
                const float p1 = __expf(sv[mt][1] - mnew);
                const float p2 = __expf(sv[mt][2] - mnew);
                const float p3 = __expf(sv[mt][3] - mnew);
                psum += (p0 + p1) + (p2 + p3);
                ushort4 pv;
                pv.x = f2bf_rne(p0); pv.y = f2bf_rne(p1);
                pv.z = f2bf_rne(p2); pv.w = f2bf_rne(p3);
                *(ushort4*)(ldsW + m16 * 72 + (mt << 4) + (quad << 2)) = pv;
            }
            l_i = l_i * alpha + psum;
#pragma unroll
            for (int dt = 0; dt < 4; ++dt)
#pragma unroll
                for (int reg = 0; reg < 4; ++reg) acc[dt][reg] *= alpha;

            // ---- O^T += V^T @ P^T : A = V-frag from LDS ----
            const bf16x8 p0 = *(const bf16x8*)(ldsW + m16 * 72 + (quad << 3));
            const bf16x8 p1 = *(const bf16x8*)(ldsW + m16 * 72 + 32 + (quad << 3));
#pragma unroll
            for (int dt = 0; dt < 4; ++dt) {
                const int base = ((dt << 4) + m16) << 6;
                bf16x8 v0 = *(const bf16x8*)&kv[buf][1][base + xs0];
                bf16x8 v1 = *(const bf16x8*)&kv[buf][1][base + xs1];
                acc[dt] = __builtin_amdgcn_mfma_f32_16x16x32_bf16(v0, p0, acc[dt], 0, 0, 0);
                acc[dt] = __builtin_amdgcn_mfma_f32_16x16x32_bf16(v1, p1, acc[dt], 0, 0, 0);
            }
        }
        buf ^= 1;
    }
    #undef ISSUE_KV

    float l = l_i;
    l += __shfl_xor(l, 16);
    l += __shfl_xor(l, 32);

    u16* ob = Opart + ((size_t)p_out << 13);      // 128 rows x 64 d
    const int qin = (wave << 4) + m16;            // 0..127
#pragma unroll
    for (int dt = 0; dt < 4; ++dt) {
        ushort4 vv;
        vv.x = f2bf_rne(acc[dt][0]); vv.y = f2bf_rne(acc[dt][1]);
        vv.z = f2bf_rne(acc[dt][2]); vv.w = f2bf_rne(acc[dt][3]);
        *(ushort4*)(ob + qin * 64 + (dt << 4) + (quad << 2)) = vv;
    }
    if (quad == 0) {
        Mp[(p_out << 7) + qin] = m_i;
        Lp[(p_out << 7) + qin] = l;
    }
}

// ---------------------------------------------------------------------------
// Kernel 3: combine the 4 chunk partials per (b, i-tile, row-sixteenth).
// Grid 1024, 256 thr; ushort4 reads / float4 writes.
// ---------------------------------------------------------------------------
__global__ __launch_bounds__(256) void combine_kernel(
        const u16* __restrict__ Opart, const float* __restrict__ Mp,
        const float* __restrict__ Lp, float* __restrict__ out) {
    __shared__ float sm[4][16];
    __shared__ float sl[4][16];
    const int bi = blockIdx.x >> 3;          // b*32 + i  (0..127)
    const int rq = blockIdx.x & 7;           // row 16-group within 128
    const int pidbase = bi << 2;
    const int t = threadIdx.x;
    if (t < 64) {
        const int cc = t >> 4, rr = t & 15;
        sm[cc][rr] = Mp[((pidbase + cc) << 7) + (rq << 4) + rr];
        sl[cc][rr] = Lp[((pidbase + cc) << 7) + (rq << 4) + rr];
    }
    __syncthreads();

    const int row_l = t >> 4;                // 0..15
    const int c4    = (t & 15) << 2;         // col base
    const int row   = (rq << 4) + row_l;     // 0..127 within i-tile

    const float M = fmaxf(fmaxf(sm[0][row_l], sm[1][row_l]),
                          fmaxf(sm[2][row_l], sm[3][row_l]));
    float n0 = 0.f, n1 = 0.f, n2 = 0.f, n3 = 0.f, den = 0.f;
#pragma unroll
    for (int cc = 0; cc < 4; ++cc) {
        const float w = __expf(sm[cc][row_l] - M);
        den += w * sl[cc][row_l];
        const ushort4 op = *(const ushort4*)&Opart[
                ((size_t)(pidbase + cc) << 13) + row * 64 + c4];
        n0 += w * bf2f(op.x); n1 += w * bf2f(op.y);
        n2 += w * bf2f(op.z); n3 += w * bf2f(op.w);
    }
    const float rd = 1.0f / den;
    float4 o; o.x = n0 * rd; o.y = n1 * rd; o.z = n2 * rd; o.w = n3 * rd;
    const int brow = (bi >> 5) * SEQ + ((bi & 31) << 7) + row;
    *(float4*)&out[((size_t)brow << 6) + c4] = o;
}

// ---------------------------------------------------------------------------
extern "C" void kernel_launch(void* const* d_in, const int* in_sizes, int n_in,
                              void* d_out, int out_size, void* d_ws, size_t ws_size,
                              hipStream_t stream) {
    const float* x  = (const float*)d_in[0];
    const float* Wq = (const float*)d_in[1];
    const float* Wk = (const float*)d_in[2];
    const float* Wv = (const float*)d_in[3];
    float* out = (float*)d_out;

    char* ws = (char*)d_ws;
    u16* Qw    = (u16*)(ws);                        // 2 MB
    u16* Kw    = (u16*)(ws + (2u << 20));           // 2 MB
    u16* Vt    = (u16*)(ws + (4u << 20));           // 2 MB  [b][64][T]
    u16* Wt    = (u16*)(ws + (6u << 20));           // 384 KB
    u16* Opart = (u16*)(ws + (13u << 19));          // 8 MB
    float* Mp  = (float*)(ws + (29u << 19));        // 256 KB
    float* Lp  = (float*)(ws + (59u << 18));        // 256 KB

    wt_kernel<<<768, 256, 0, stream>>>(Wq, Wk, Wv, Wt);
    qkv_kernel<<<192, 512, 0, stream>>>(x, Wt, Qw, Kw, Vt);
    attn_part_kernel<<<512, 512, 0, stream>>>(Qw, Kw, Vt, Opart, Mp, Lp);
    combine_kernel<<<1024, 256, 0, stream>>>(Opart, Mp, Lp, out);
}